// Round 2
// baseline (293.433 us; speedup 1.0000x reference)
//
#include <hip/hip_runtime.h>
#include <math.h>

// Problem constants (fixed by the reference).
#define NUM_K   512        // codebook entries
#define DIM     64         // embedding dim (== C)
#define NROWS   131072     // 32*64*64 flattened (b,h,w) rows
#define NELEM   8388608    // NROWS*DIM
// d_out layout (float32, concatenated in return order):
// [0] loss ; [1..1+NELEM) quantized NCHW ; [1+NELEM] perplexity ;
// [2+NELEM..) codebook_indices (as float)
#define Q_OFF    1
#define PERP_OFF 8388609
#define IDX_OFF  8388610

// ws layout: [0,4) float loss_sum ; [16,16+2048) uint counts[512] ;
//            [4096,4096+2048) float wsq[512]

// wsq[k] must be BITWISE numpy's np.sum(weight**2, axis=1):
// pairwise leaf (n=64): 8 accumulators r[j] = q[j]+q[j+8]+...+q[j+56]
// (sequential), combine ((r0+r1)+(r2+r3))+((r4+r5)+(r6+r7)).
// __fmul_rn/__fadd_rn prevent FMA contraction.
__global__ __launch_bounds__(256) void vq_wsq(const float* __restrict__ w,
                                              float* __restrict__ wsq) {
    int k = blockIdx.x * 256 + threadIdx.x;
    if (k >= NUM_K) return;
    const float* wk = w + k * DIM;
    float r[8];
#pragma unroll
    for (int j = 0; j < 8; ++j) r[j] = __fmul_rn(wk[j], wk[j]);
#pragma unroll
    for (int t = 1; t < 8; ++t)
#pragma unroll
        for (int j = 0; j < 8; ++j)
            r[j] = __fadd_rn(r[j], __fmul_rn(wk[8 * t + j], wk[8 * t + j]));
    float res = __fadd_rn(
        __fadd_rn(__fadd_rn(r[0], r[1]), __fadd_rn(r[2], r[3])),
        __fadd_rn(__fadd_rn(r[4], r[5]), __fadd_rn(r[6], r[7])));
    wsq[k] = res;
}

__global__ __launch_bounds__(256) void vq_main(
        const float* __restrict__ x,      // NCHW input
        const float* __restrict__ w,      // [512,64] codebook
        const float* __restrict__ wsq,    // [512] numpy-bitwise ||w_k||^2
        float* __restrict__ out_q,        // d_out + Q_OFF (NCHW)
        float* __restrict__ out_idx,      // d_out + IDX_OFF
        float* __restrict__ loss_sum,     // ws accumulator
        unsigned* __restrict__ counts) {  // ws histogram [512]
    __shared__ unsigned hcnt[NUM_K];
    __shared__ float wred[4];
    const int tid = threadIdx.x;
    for (int i = tid; i < NUM_K; i += 256) hcnt[i] = 0;
    __syncthreads();

    const int n  = blockIdx.x * 256 + tid;   // flattened (b,h,w) row
    const int b  = n >> 12;
    const int hw = n & 4095;
    const float* xp = x + (size_t)b * 262144 + hw;

    // Row's 64 channel values (stride 4096 floats, lanes coalesced).
    float xr[DIM];
#pragma unroll
    for (int c = 0; c < DIM; ++c) xr[c] = xp[(size_t)c * 4096];

    // xsq: any fp32 summation works — it is an on-grid row-constant shift of
    // the reference's d(n,k); the per-k rounding of fl(xsq+wsq[k]) depends
    // only on wsq[k] and the binade grid, not xsq's low bits.
    float p0 = 0.f, p1 = 0.f, p2 = 0.f, p3 = 0.f;
#pragma unroll
    for (int c = 0; c < DIM; c += 4) {
        p0 = fmaf(xr[c + 0], xr[c + 0], p0);
        p1 = fmaf(xr[c + 1], xr[c + 1], p1);
        p2 = fmaf(xr[c + 2], xr[c + 2], p2);
        p3 = fmaf(xr[c + 3], xr[c + 3], p3);
    }
    const float xsq = __fadd_rn(__fadd_rn(p0, p1), __fadd_rn(p2, p3));

    // Reference-matching score: d = fl(fl(xsq + wsq[k]) - fl(2*dot)).
    // dot is a SEQUENTIAL fma chain over c=0..63 — bitwise-matching OpenBLAS
    // sgemm's per-element k-ascending single-accumulator fma microkernel.
    float best = 3.4e38f;
    int bk = 0;
    for (int k = 0; k < NUM_K; ++k) {
        const float4* wk = (const float4*)(w + (size_t)k * DIM);  // wave-uniform
        float dot = 0.f;
#pragma unroll
        for (int j = 0; j < DIM / 4; ++j) {
            float4 v = wk[j];
            dot = fmaf(xr[4 * j + 0], v.x, dot);
            dot = fmaf(xr[4 * j + 1], v.y, dot);
            dot = fmaf(xr[4 * j + 2], v.z, dot);
            dot = fmaf(xr[4 * j + 3], v.w, dot);
        }
        float s = __fsub_rn(__fadd_rn(xsq, wsq[k]), __fmul_rn(2.0f, dot));
        if (s < best) { best = s; bk = k; }  // strict < = np.argmin first-min
    }

    atomicAdd(&hcnt[bk], 1u);

    // Epilogue: gather code row bk, write quantized (NCHW), accumulate MSE.
    float dsum = 0.f;
    const float4* wb = (const float4*)(w + (size_t)bk * DIM);
    float* oq = out_q + (size_t)b * 262144 + hw;
#pragma unroll
    for (int j = 0; j < DIM / 4; ++j) {
        float4 v = wb[j];
        float d0 = v.x - xr[4 * j + 0];
        float d1 = v.y - xr[4 * j + 1];
        float d2 = v.z - xr[4 * j + 2];
        float d3 = v.w - xr[4 * j + 3];
        dsum = fmaf(d0, d0, dsum);
        dsum = fmaf(d1, d1, dsum);
        dsum = fmaf(d2, d2, dsum);
        dsum = fmaf(d3, d3, dsum);
        oq[(size_t)(4 * j + 0) * 4096] = v.x;
        oq[(size_t)(4 * j + 1) * 4096] = v.y;
        oq[(size_t)(4 * j + 2) * 4096] = v.z;
        oq[(size_t)(4 * j + 3) * 4096] = v.w;
    }
    out_idx[n] = (float)bk;

    // Loss partial: wave shuffle reduce (64 lanes) -> LDS -> one atomic/block.
#pragma unroll
    for (int off = 32; off > 0; off >>= 1) dsum += __shfl_down(dsum, off);
    if ((tid & 63) == 0) wred[tid >> 6] = dsum;
    __syncthreads();
    if (tid == 0)
        atomicAdd(loss_sum, (wred[0] + wred[1]) + (wred[2] + wred[3]));

    // Histogram flush: at most 2 global atomics per thread.
    for (int i = tid; i < NUM_K; i += 256) {
        unsigned c = hcnt[i];
        if (c) atomicAdd(&counts[i], c);
    }
}

__global__ __launch_bounds__(512) void vq_final(
        const unsigned* __restrict__ counts,
        const float* __restrict__ loss_sum,
        float* __restrict__ out) {
    __shared__ float red[8];
    const int tid = threadIdx.x;
    float p = (float)counts[tid] * (1.f / (float)NROWS);  // /131072 exact
    float t = p * logf(p + 1e-10f);
#pragma unroll
    for (int off = 32; off > 0; off >>= 1) t += __shfl_down(t, off);
    if ((tid & 63) == 0) red[tid >> 6] = t;
    __syncthreads();
    if (tid == 0) {
        float s = 0.f;
#pragma unroll
        for (int i = 0; i < 8; ++i) s += red[i];
        out[PERP_OFF] = expf(-s);
        // loss = q_latent + 0.25*e_latent = 1.25 * MSE (forward values equal)
        out[0] = loss_sum[0] * (1.25f / (float)NELEM);
    }
}

extern "C" void kernel_launch(void* const* d_in, const int* in_sizes, int n_in,
                              void* d_out, int out_size, void* d_ws, size_t ws_size,
                              hipStream_t stream) {
    const float* x = (const float*)d_in[0];
    const float* w = (const float*)d_in[1];
    float* out = (float*)d_out;
    char* ws = (char*)d_ws;
    float* loss_sum = (float*)ws;
    unsigned* counts = (unsigned*)(ws + 16);
    float* wsq = (float*)(ws + 4096);

    // ws is re-poisoned to 0xAA before every launch: zero accumulators.
    hipMemsetAsync(d_ws, 0, 2064, stream);

    vq_wsq<<<2, 256, 0, stream>>>(w, wsq);
    vq_main<<<NROWS / 256, 256, 0, stream>>>(x, w, wsq,
                                             out + Q_OFF, out + IDX_OFF,
                                             loss_sum, counts);
    vq_final<<<1, 512, 0, stream>>>(counts, loss_sum, out);
}